// Round 1
// baseline (107.669 us; speedup 1.0000x reference)
//
#include <hip/hip_runtime.h>
#include <math.h>

#define NEG_INF (-INFINITY)

__device__ __forceinline__ float nll3(float l0, float l1, float l2) {
    float m = fmaxf(l0, fmaxf(l1, l2));
    float e0 = __expf(l0 - m);
    float e1 = __expf(l1 - m);
    float e2 = __expf(l2 - m);
    return __logf(e0 + e1 + e2) - (l0 - m);
}

// ---------------------------------------------------------------------------
// Depth-2-pipelined, vectorized, barrier/atomic-free neg-loss strip.
// Wave layout: NG = 64/(W/4) row-groups x LR = W/4 lanes; lane group g holds
// input row h0-1+g as a float4. Groups 0..NR-1 emit output rows h0..h0+NR-1.
// Register plane-sets A (consume now), B (+1), C (+2): step s consumes loads
// issued at step s-2, giving ~2 compute-steps of latency slack per wave.
// All loads unconditional (clamped addresses, -inf selection afterwards).
// TD=4 (was 8): doubles wave count (6928 total -> ~27 waves/CU offered) to
// cover the exposed load latency with TLP; depth-halo amplification rises
// 1.25->1.5 but the redundant re-reads are L3-resident.
// ---------------------------------------------------------------------------
template<int W, int NR, int TD, int D, int H>
__device__ void neg_strip_p2(int uid, int lane,
                             const float* __restrict__ logit,
                             const float* __restrict__ pg,
                             float2* __restrict__ slot) {
    constexpr int LR = W / 4;          // lanes per row
    constexpr int NI = NR + 2;         // input rows used
    constexpr int HG = H / NR;
    constexpr int DT = D / TD;
    const int q = lane % LR;
    const int g = lane / LR;

    int t = uid;
    const int hg = t % HG; t /= HG;
    const int dt = t % DT; t /= DT;
    const int ba = t;                  // b*3 + a (A == 3)
    const int a = ba % 3, b = ba / 3;
    const int h0 = hg * NR, d0 = dt * TD;
    const int HW = H * W;

    const long S = (long)D * HW;
    const float* lb  = logit + ((long)b * 9 + a) * S;   // class-0 plane
    const long  cs   = 3 * S;                           // A*S
    const float* pgb = pg + (long)ba * S;

    const int jrow = h0 - 1 + g;
    const bool hv = (jrow >= 0) && (jrow < H) && (g < NI);
    const int hcl = min(max(jrow, 0), H - 1);
    const int rowoff = hcl * W + 4 * q;
    const int prowoff = (h0 + min(g, NR - 1)) * W + 4 * q;

    // plane-sets: A = consume at this step, B = +1, C = +2 (freshly loaded)
    float4 A0, A1, A2, B0, B1, B2, C0, C1, C2;
    float4 GA, GB, GC;
    bool vA, vB, vC;

    {   // prologue: planes d0-1 and d0
        const float* p = lb + (long)max(d0 - 1, 0) * HW + rowoff;
        A0 = *(const float4*)p;
        A1 = *(const float4*)(p + cs);
        A2 = *(const float4*)(p + 2 * cs);
        vA = (d0 - 1 >= 0);
        const float* p2 = lb + (long)d0 * HW + rowoff;
        B0 = *(const float4*)p2;
        B1 = *(const float4*)(p2 + cs);
        B2 = *(const float4*)(p2 + 2 * cs);
        vB = true;
        GA = make_float4(0.f, 0.f, 0.f, 0.f);   // pg consumed only from s>=2
        GB = make_float4(0.f, 0.f, 0.f, 0.f);
    }

    float vm0[4], vm1[4], cc1[4];
#pragma unroll
    for (int i = 0; i < 4; ++i) { vm0[i] = NEG_INF; vm1[i] = NEG_INF; cc1[i] = 0.f; }

    float loss = 0.f, cnt = 0.f;

#pragma unroll
    for (int s = 0; s <= TD + 1; ++s) {                 // s compile-time
        // ---- depth-2 prefetch: class plane d0+1+s, pg plane d0+s ----
        if (s <= TD - 1) {                              // compile-time guard
            const int pd = d0 + 1 + s;                  // may equal D -> clamp
            const float* p = lb + (long)min(pd, D - 1) * HW + rowoff;
            C0 = *(const float4*)p;
            C1 = *(const float4*)(p + cs);
            C2 = *(const float4*)(p + 2 * cs);
            vC = (pd < D);
            GC = *(const float4*)(pgb + (long)(d0 + s) * HW + prowoff); // < D
        } else {
            vC = false;
            C0 = C1 = C2 = make_float4(0.f, 0.f, 0.f, 0.f);
            GC = make_float4(0.f, 0.f, 0.f, 0.f);
        }

        // ---- nll of plane d0-1+s (set A) ----
        float nvv[4];
        {
            const bool vv = vA && hv;
            nvv[0] = vv ? nll3(A0.x, A1.x, A2.x) : NEG_INF;
            nvv[1] = vv ? nll3(A0.y, A1.y, A2.y) : NEG_INF;
            nvv[2] = vv ? nll3(A0.z, A1.z, A2.z) : NEG_INF;
            nvv[3] = vv ? nll3(A0.w, A1.w, A2.w) : NEG_INF;
        }

        // ---- in-row 3-wide max ----
        float le = __shfl(nvv[3], lane - 1);
        float re = __shfl(nvv[0], lane + 1);
        le = (q == 0)      ? NEG_INF : le;
        re = (q == LR - 1) ? NEG_INF : re;
        float rm[4];
        rm[0] = fmaxf(le,     fmaxf(nvv[0], nvv[1]));
        rm[1] = fmaxf(nvv[0], fmaxf(nvv[1], nvv[2]));
        rm[2] = fmaxf(nvv[1], fmaxf(nvv[2], nvv[3]));
        rm[3] = fmaxf(nvv[2], fmaxf(nvv[3], re));

        // ---- cross-row: group r gets rows r+1, r+2, center row r+1 ----
        float rmA[4], rmB[4], ctr[4];
#pragma unroll
        for (int i = 0; i < 4; ++i) {
            rmA[i] = __shfl(rm[i],  lane + LR);
            rmB[i] = __shfl(rm[i],  lane + 2 * LR);
            ctr[i] = __shfl(nvv[i], lane + LR);
        }

        // ---- 3-deep d-window + emit (center plane d0+s-2, pg in GA) ----
        const float pgv[4] = {GA.x, GA.y, GA.z, GA.w};
#pragma unroll
        for (int i = 0; i < 4; ++i) {
            float hw2 = fmaxf(rm[i], fmaxf(rmA[i], rmB[i]));
            if (s >= 2 && g < NR && pgv[i] == -1.0f) {
                float mp = fmaxf(vm0[i], fmaxf(vm1[i], hw2));
                if (mp == cc1[i]) {
                    float pn = __expf(-cc1[i]);
                    float wn = (1.f - pn) * (1.f - pn);
                    loss += cc1[i] * wn;
                    cnt  += wn;
                }
            }
            vm0[i] = vm1[i]; vm1[i] = hw2; cc1[i] = ctr[i];
        }

        // ---- rotate pipeline sets ----
        GA = GB; GB = GC;
        A0 = B0; A1 = B1; A2 = B2; vA = vB;
        B0 = C0; B1 = C1; B2 = C2; vB = vC;
    }

#pragma unroll
    for (int off = 32; off > 0; off >>= 1) {
        loss += __shfl_down(loss, off);
        cnt  += __shfl_down(cnt, off);
    }
    if (lane == 0) slot[uid] = make_float2(loss, cnt);
}

// ---------------------------------------------------------------------------
// Positive gathers: 8 waves per level, 1 item per lane (B*P = 512).
// ---------------------------------------------------------------------------
__device__ void pos_wave8(int sub, int lane,
                          const float* __restrict__ logit,
                          const float* __restrict__ prob_gt,
                          const int* __restrict__ coord,
                          const float* __restrict__ wcls,
                          float2* __restrict__ slot,
                          int D, int H, int W) {
    const int A = 3, P = 128;
    const long S = (long)D * H * W;
    const int i = sub * 64 + lane;          // < 512
    const int b = i / P;
    const int* c = coord + (long)i * 4;
    const int a = c[0];
    float loss = 0.f, cnt = 0.f;
    if (a > -1) {
        const int d = c[1], h = c[2], w = c[3];
        const long s = ((long)d * H + h) * W + w;
        const int cls = (int)prob_gt[((long)b * A + a) * S + s];
        const float* lp = logit + ((long)b * 3 * A + a) * S + s;
        float l0 = lp[0];
        float l1 = lp[(long)A * S];
        float l2 = lp[2L * A * S];
        float m = fmaxf(l0, fmaxf(l1, l2));
        float e0 = __expf(l0 - m);
        float e1 = __expf(l1 - m);
        float e2 = __expf(l2 - m);
        float lsum = __logf(e0 + e1 + e2);
        float lc = (cls == 0) ? l0 : ((cls == 1) ? l1 : l2);
        float lpc = (lc - m) - lsum;
        float pt = __expf(lpc);
        float wp = (1.f - pt) * (1.f - pt) * wcls[cls];
        loss = (-lpc) * wp;
        cnt = wp;
    }
#pragma unroll
    for (int off = 32; off > 0; off >>= 1) {
        loss += __shfl_down(loss, off);
        cnt  += __shfl_down(cnt, off);
    }
    if (lane == 0) *slot = make_float2(loss, cnt);
}

// ---------------------------------------------------------------------------
// Work split (wave-indexed, barrier-free):
//   L0: W=64, NR=2, TD=4 -> 12*32*16 = 6144 waves
//   L1: W=32, NR=4, TD=4 -> 12*8*8   =  768 waves
//   pos: 8 + 8 waves                      TOTAL 6928 -> 1732 blocks
// ---------------------------------------------------------------------------
#define NW0 6144
#define NW1 768
#define NWP 16
#define NUNEG (NW0 + NW1)
#define TOTAL_WAVES (NW0 + NW1 + NWP)   // 6928 = 1732 * 4

__global__ __launch_bounds__(256)
void mega_kernel(const float* __restrict__ logit0,
                 const float* __restrict__ logit1,
                 const float* __restrict__ pg0,
                 const float* __restrict__ pg1,
                 const int* __restrict__ coord0,
                 const int* __restrict__ coord1,
                 const float* __restrict__ wcls,
                 float2* __restrict__ ws) {
    const int gw = blockIdx.x * 4 + (threadIdx.x >> 6);
    const int lane = threadIdx.x & 63;
    float2* wsneg = ws;
    float2* wspos = ws + NUNEG;
    if (gw < NW0) {
        neg_strip_p2<64, 2, 4, 64, 64>(gw, lane, logit0, pg0, wsneg);
    } else if (gw < NW0 + NW1) {
        neg_strip_p2<32, 4, 4, 32, 32>(gw - NW0, lane, logit1, pg1, wsneg + NW0);
    } else if (gw < NW0 + NW1 + 8) {
        const int sub = gw - NW0 - NW1;
        pos_wave8(sub, lane, logit0, pg0, coord0, wcls, wspos + sub, 64, 64, 64);
    } else {
        const int sub = gw - NW0 - NW1 - 8;
        pos_wave8(sub, lane, logit1, pg1, coord1, wcls, wspos + 8 + sub, 32, 32, 32);
    }
}

// ---------------------------------------------------------------------------
// Final reduction: one 1024-thread block sums all slots, writes out[0..3].
// ---------------------------------------------------------------------------
__global__ __launch_bounds__(1024)
void final_reduce(const float2* __restrict__ ws, float* __restrict__ out) {
    const float2* wsneg = ws;
    const float2* wspos = ws + NUNEG;
    float ln = 0.f, cn = 0.f, lp = 0.f, cp = 0.f;
    for (int i = threadIdx.x; i < NUNEG; i += 1024) {
        float2 v = wsneg[i]; ln += v.x; cn += v.y;
    }
    if (threadIdx.x < NWP) {
        float2 v = wspos[threadIdx.x]; lp = v.x; cp = v.y;
    }
#pragma unroll
    for (int off = 32; off > 0; off >>= 1) {
        ln += __shfl_down(ln, off); cn += __shfl_down(cn, off);
        lp += __shfl_down(lp, off); cp += __shfl_down(cp, off);
    }
    __shared__ float s[16][4];
    const int wv = threadIdx.x >> 6;
    if ((threadIdx.x & 63) == 0) {
        s[wv][0] = ln; s[wv][1] = cn; s[wv][2] = lp; s[wv][3] = cp;
    }
    __syncthreads();
    if (threadIdx.x == 0) {
        float a = 0.f, b = 0.f, c = 0.f, d = 0.f;
#pragma unroll
        for (int i = 0; i < 16; ++i) {
            a += s[i][0]; b += s[i][1]; c += s[i][2]; d += s[i][3];
        }
        out[0] = c;   // loss_pos
        out[1] = a;   // loss_neg
        out[2] = d;   // count_pos
        out[3] = b;   // count_neg
    }
}

extern "C" void kernel_launch(void* const* d_in, const int* in_sizes, int n_in,
                              void* d_out, int out_size, void* d_ws, size_t ws_size,
                              hipStream_t stream) {
    const float* logit0   = (const float*)d_in[0];
    const float* logit1   = (const float*)d_in[1];
    const float* prob_gt0 = (const float*)d_in[2];
    const float* prob_gt1 = (const float*)d_in[3];
    const int*   coord0   = (const int*)d_in[4];
    const int*   coord1   = (const int*)d_in[5];
    const float* wcls     = (const float*)d_in[6];
    float* out = (float*)d_out;
    float2* ws = (float2*)d_ws;

    mega_kernel<<<TOTAL_WAVES / 4, 256, 0, stream>>>(
        logit0, logit1, prob_gt0, prob_gt1, coord0, coord1, wcls, ws);
    final_reduce<<<1, 1024, 0, stream>>>(ws, out);
}

// Round 2
// 105.275 us; speedup vs baseline: 1.0227x; 1.0227x over previous
//
#include <hip/hip_runtime.h>
#include <math.h>

#define NEG_INF (-INFINITY)

__device__ __forceinline__ float nll3(float l0, float l1, float l2) {
    float m = fmaxf(l0, fmaxf(l1, l2));
    float e0 = __expf(l0 - m);
    float e1 = __expf(l1 - m);
    float e2 = __expf(l2 - m);
    return __logf(e0 + e1 + e2) - (l0 - m);
}

__device__ __forceinline__ float4 fmax4(float4 a, float4 b) {
    return make_float4(fmaxf(a.x, b.x), fmaxf(a.y, b.y),
                       fmaxf(a.z, b.z), fmaxf(a.w, b.w));
}

// ---------------------------------------------------------------------------
// LDS-tiled neg loss: one block = one (b,a) x z-tile(ZT) x h-tile(HT).
// Per plane z: P1 compute nll once into LDS slab (HT+2 rows, halo),
// P2 separable 3x3 in-plane max (vertical from LDS, horizontal via 2 shuffles)
// into rolling hv[3] slabs, P3 emit plane z-1 comparing center nll vs
// max of 3 hv slabs (the 3x3x3 maxpool) where prob_gt == -1.
// Global loads (class triple + pg) are register-pipelined one full plane
// ahead, so their latency hides under P1+P2+P3 of the previous plane.
// 2 barriers per plane. Each nll computed once per tile (amp 1.5z x 1.125h
// vs 2.5x in the old shuffle-strip design), no register-rotation storm.
// ---------------------------------------------------------------------------
template<int W, int HT, int ZT, int D, int H>
__device__ void neg_block(int ub, int tid,
                          const float* __restrict__ logit,
                          const float* __restrict__ pg,
                          float2* __restrict__ slot,
                          float* lds, float2* red) {
    constexpr int LQ = W / 4;            // float4 quads per row
    constexpr int SR = W + 4;            // padded LDS row stride (floats)
    constexpr int SROWS = HT + 2;        // nll slab rows (with h halo)
    constexpr int QS = SROWS * LQ;       // quads per nll slab (<= 512)
    constexpr int HW = H * W;
    constexpr int ZTI = D / ZT;
    constexpr int HTI = H / HT;
    constexpr int NLL_SZ = SROWS * SR;
    constexpr int HV_OFF = 3 * NLL_SZ;
    constexpr int HV_SZ = HT * SR;

    int t = ub;
    const int ht = t % HTI; t /= HTI;
    const int zt = t % ZTI; t /= ZTI;
    const int ba = t;
    const int a = ba % 3, b = ba / 3;
    const int z0 = zt * ZT, h0 = ht * HT;

    const long S = (long)D * HW;
    const long cs = 3 * S;
    const float* lb  = logit + ((long)b * 9 + a) * S;
    const float* pgb = pg + (long)ba * S;

    // per-thread invariants
    const int er = tid / LQ;             // 0..HT-1 (HT*LQ == 256)
    const int q  = tid % LQ;
    const int lane = tid & 63;
    const int l_er = er * SR + 4 * q;    // hv slab offset / nll row er
    const int po = (h0 + er) * W + 4 * q;   // pg plane offset

    // P1 round invariants (round r covers quads tid + 256*r)
    int roff[2]; bool rok[2];
#pragma unroll
    for (int r = 0; r < 2; ++r) {
        const int k = tid + 256 * r;
        const int row = k / LQ, qq = k % LQ;
        const int h = h0 - 1 + row;
        rok[r]  = (k < QS) && (h >= 0) && (h < H);
        roff[r] = min(max(h, 0), H - 1) * W + 4 * qq;
    }

    float4 rA[2][3] = {}, rB[2][3] = {};
    float4 pgA = {}, pgB = {};
    bool pvA, pvB = false;

    auto issue = [&](float4 (&rg)[2][3], int zp) -> bool {
        const bool pv = (zp >= 0) && (zp < D);
        if (pv) {
#pragma unroll
            for (int r = 0; r < 2; ++r) {
                if (tid + 256 * r < QS) {
                    const float* p = lb + (long)zp * HW + roff[r];
                    rg[r][0] = *(const float4*)p;
                    rg[r][1] = *(const float4*)(p + cs);
                    rg[r][2] = *(const float4*)(p + 2 * cs);
                }
            }
        }
        return pv;
    };

    pvA = issue(rA, z0 - 1);

    float loss = 0.f, cnt = 0.f;

#pragma unroll
    for (int zi = 0; zi <= ZT + 1; ++zi) {
        const int zc = z0 - 1 + zi;
        // ---- prefetch next class plane + pg plane (consumed next iter) ----
        if (zi <= ZT) pvB = issue(rB, zc + 1);
        if (zi >= 1 && zi <= ZT)
            pgB = *(const float4*)(pgb + (long)zc * HW + po);

        // ---- P1: nll slab for plane zc (computed once per voxel) ----
        {
            float* nb = lds + (zi % 3) * NLL_SZ;
#pragma unroll
            for (int r = 0; r < 2; ++r) {
                const int k = tid + 256 * r;
                if (k < QS) {
                    const int row = k / LQ, qq = k % LQ;
                    const bool ok = pvA && rok[r];
                    float4 n;
                    n.x = ok ? nll3(rA[r][0].x, rA[r][1].x, rA[r][2].x) : NEG_INF;
                    n.y = ok ? nll3(rA[r][0].y, rA[r][1].y, rA[r][2].y) : NEG_INF;
                    n.z = ok ? nll3(rA[r][0].z, rA[r][1].z, rA[r][2].z) : NEG_INF;
                    n.w = ok ? nll3(rA[r][0].w, rA[r][1].w, rA[r][2].w) : NEG_INF;
                    *(float4*)(nb + row * SR + 4 * qq) = n;
                }
            }
        }
        __syncthreads();

        // ---- P2: separable in-plane 3x3 max -> hv[zi%3] ----
        {
            const float* nb = lds + (zi % 3) * NLL_SZ;
            float* hb = lds + HV_OFF + (zi % 3) * HV_SZ;
            float4 v0 = *(const float4*)(nb + l_er);
            float4 v1 = *(const float4*)(nb + l_er + SR);
            float4 v2 = *(const float4*)(nb + l_er + 2 * SR);
            float4 vm = fmax4(v0, fmax4(v1, v2));
            float le = __shfl(vm.w, lane - 1);
            float re = __shfl(vm.x, lane + 1);
            le = (q == 0)      ? NEG_INF : le;
            re = (q == LQ - 1) ? NEG_INF : re;
            float4 hv;
            hv.x = fmaxf(le,   fmaxf(vm.x, vm.y));
            hv.y = fmaxf(vm.x, fmaxf(vm.y, vm.z));
            hv.z = fmaxf(vm.y, fmaxf(vm.z, vm.w));
            hv.w = fmaxf(vm.z, fmaxf(vm.w, re));
            *(float4*)(hb + l_er) = hv;
        }
        __syncthreads();

        // ---- P3: emit plane ze = zc-1 (3x3x3 max = max of 3 hv slabs) ----
        if (zi >= 2) {
            const float* nbm = lds + ((zi - 1) % 3) * NLL_SZ;
            const float* hb0 = lds + HV_OFF + ((zi - 2) % 3) * HV_SZ;
            const float* hb1 = lds + HV_OFF + ((zi - 1) % 3) * HV_SZ;
            const float* hb2 = lds + HV_OFF + (zi % 3) * HV_SZ;
            float4 nc = *(const float4*)(nbm + l_er + SR);     // center row
            float4 m  = fmax4(*(const float4*)(hb0 + l_er),
                        fmax4(*(const float4*)(hb1 + l_er),
                              *(const float4*)(hb2 + l_er)));
            const float pgv[4] = {pgA.x, pgA.y, pgA.z, pgA.w};
            const float ncv[4] = {nc.x, nc.y, nc.z, nc.w};
            const float mv[4]  = {m.x, m.y, m.z, m.w};
#pragma unroll
            for (int i = 0; i < 4; ++i) {
                if (pgv[i] == -1.0f && mv[i] == ncv[i]) {
                    float pn = __expf(-ncv[i]);
                    float wn = (1.f - pn) * (1.f - pn);
                    loss += ncv[i] * wn;
                    cnt  += wn;
                }
            }
        }

        // ---- rotate prefetch registers ----
        pvA = pvB;
#pragma unroll
        for (int r = 0; r < 2; ++r)
#pragma unroll
            for (int c = 0; c < 3; ++c) rA[r][c] = rB[r][c];
        pgA = pgB;
    }

    // ---- block reduction ----
#pragma unroll
    for (int off = 32; off > 0; off >>= 1) {
        loss += __shfl_down(loss, off);
        cnt  += __shfl_down(cnt, off);
    }
    if (lane == 0) red[tid >> 6] = make_float2(loss, cnt);
    __syncthreads();
    if (tid == 0) {
        float sx = 0.f, sy = 0.f;
#pragma unroll
        for (int i = 0; i < 4; ++i) { sx += red[i].x; sy += red[i].y; }
        *slot = make_float2(sx, sy);
    }
}

// ---------------------------------------------------------------------------
// Positive gathers: 8 waves per level, 1 item per lane (B*P = 512).
// ---------------------------------------------------------------------------
__device__ void pos_wave8(int sub, int lane,
                          const float* __restrict__ logit,
                          const float* __restrict__ prob_gt,
                          const int* __restrict__ coord,
                          const float* __restrict__ wcls,
                          float2* __restrict__ slot,
                          int D, int H, int W) {
    const int A = 3, P = 128;
    const long S = (long)D * H * W;
    const int i = sub * 64 + lane;          // < 512
    const int b = i / P;
    const int* c = coord + (long)i * 4;
    const int a = c[0];
    float loss = 0.f, cnt = 0.f;
    if (a > -1) {
        const int d = c[1], h = c[2], w = c[3];
        const long s = ((long)d * H + h) * W + w;
        const int cls = (int)prob_gt[((long)b * A + a) * S + s];
        const float* lp = logit + ((long)b * 3 * A + a) * S + s;
        float l0 = lp[0];
        float l1 = lp[(long)A * S];
        float l2 = lp[2L * A * S];
        float m = fmaxf(l0, fmaxf(l1, l2));
        float e0 = __expf(l0 - m);
        float e1 = __expf(l1 - m);
        float e2 = __expf(l2 - m);
        float lsum = __logf(e0 + e1 + e2);
        float lc = (cls == 0) ? l0 : ((cls == 1) ? l1 : l2);
        float lpc = (lc - m) - lsum;
        float pt = __expf(lpc);
        float wp = (1.f - pt) * (1.f - pt) * wcls[cls];
        loss = (-lpc) * wp;
        cnt = wp;
    }
#pragma unroll
    for (int off = 32; off > 0; off >>= 1) {
        loss += __shfl_down(loss, off);
        cnt  += __shfl_down(cnt, off);
    }
    if (lane == 0) *slot = make_float2(loss, cnt);
}

// ---------------------------------------------------------------------------
// Work split (block-indexed):
//   L0: 12 (b,a) x 16 z-tiles(ZT=4) x 4 h-tiles(HT=16) = 768 blocks
//   L1: 12 (b,a) x  8 z-tiles(ZT=4) x 1 h-tile (HT=32) =  96 blocks
//   pos: 4 blocks (16 waves)                     TOTAL 868 blocks
// ---------------------------------------------------------------------------
#define NB0 768
#define NB1 96
#define NBNEG (NB0 + NB1)
#define NBP 4
#define TOTAL_BLOCKS (NBNEG + NBP)
#define NWP 16

__global__ __launch_bounds__(256)
void mega_kernel(const float* __restrict__ logit0,
                 const float* __restrict__ logit1,
                 const float* __restrict__ pg0,
                 const float* __restrict__ pg1,
                 const int* __restrict__ coord0,
                 const int* __restrict__ coord1,
                 const float* __restrict__ wcls,
                 float2* __restrict__ ws) {
    __shared__ float lds[7128];          // max(L0: 6936, L1: 7128) floats
    __shared__ float2 red[4];
    const int bid = blockIdx.x;
    const int tid = threadIdx.x;
    float2* wsneg = ws;
    float2* wspos = ws + NBNEG;
    if (bid < NB0) {
        neg_block<64, 16, 4, 64, 64>(bid, tid, logit0, pg0, wsneg + bid, lds, red);
    } else if (bid < NBNEG) {
        neg_block<32, 32, 4, 32, 32>(bid - NB0, tid, logit1, pg1, wsneg + bid, lds, red);
    } else {
        const int gwl = (bid - NBNEG) * 4 + (tid >> 6);
        const int lane = tid & 63;
        if (gwl < 8)
            pos_wave8(gwl, lane, logit0, pg0, coord0, wcls, wspos + gwl, 64, 64, 64);
        else
            pos_wave8(gwl - 8, lane, logit1, pg1, coord1, wcls, wspos + gwl, 32, 32, 32);
    }
}

// ---------------------------------------------------------------------------
// Final reduction: one 1024-thread block sums all slots, writes out[0..3].
// ---------------------------------------------------------------------------
__global__ __launch_bounds__(1024)
void final_reduce(const float2* __restrict__ ws, float* __restrict__ out) {
    const float2* wsneg = ws;
    const float2* wspos = ws + NBNEG;
    float ln = 0.f, cn = 0.f, lp = 0.f, cp = 0.f;
    for (int i = threadIdx.x; i < NBNEG; i += 1024) {
        float2 v = wsneg[i]; ln += v.x; cn += v.y;
    }
    if (threadIdx.x < NWP) {
        float2 v = wspos[threadIdx.x]; lp = v.x; cp = v.y;
    }
#pragma unroll
    for (int off = 32; off > 0; off >>= 1) {
        ln += __shfl_down(ln, off); cn += __shfl_down(cn, off);
        lp += __shfl_down(lp, off); cp += __shfl_down(cp, off);
    }
    __shared__ float s[16][4];
    const int wv = threadIdx.x >> 6;
    if ((threadIdx.x & 63) == 0) {
        s[wv][0] = ln; s[wv][1] = cn; s[wv][2] = lp; s[wv][3] = cp;
    }
    __syncthreads();
    if (threadIdx.x == 0) {
        float a = 0.f, b = 0.f, c = 0.f, d = 0.f;
#pragma unroll
        for (int i = 0; i < 16; ++i) {
            a += s[i][0]; b += s[i][1]; c += s[i][2]; d += s[i][3];
        }
        out[0] = c;   // loss_pos
        out[1] = a;   // loss_neg
        out[2] = d;   // count_pos
        out[3] = b;   // count_neg
    }
}

extern "C" void kernel_launch(void* const* d_in, const int* in_sizes, int n_in,
                              void* d_out, int out_size, void* d_ws, size_t ws_size,
                              hipStream_t stream) {
    const float* logit0   = (const float*)d_in[0];
    const float* logit1   = (const float*)d_in[1];
    const float* prob_gt0 = (const float*)d_in[2];
    const float* prob_gt1 = (const float*)d_in[3];
    const int*   coord0   = (const int*)d_in[4];
    const int*   coord1   = (const int*)d_in[5];
    const float* wcls     = (const float*)d_in[6];
    float* out = (float*)d_out;
    float2* ws = (float2*)d_ws;

    mega_kernel<<<TOTAL_BLOCKS, 256, 0, stream>>>(
        logit0, logit1, prob_gt0, prob_gt1, coord0, coord1, wcls, ws);
    final_reduce<<<1, 1024, 0, stream>>>(ws, out);
}